// Round 12
// baseline (478180.566 us; speedup 1.0000x reference)
//
#include <hip/hip_runtime.h>

#define CG_ITERS 30
#define PAP_OFF 32   // scal[0..30] = rs_i (f32) ; scal[32+it] = pAp_it (f32)
#define TILE 8192
#define CHAIN_TB 256

__device__ __forceinline__ float fadd32(float a, float b){ return __fadd_rn(a,b); }
__device__ __forceinline__ float fsub32(float a, float b){ return __fsub_rn(a,b); }
__device__ __forceinline__ float fmul32(float a, float b){ return __fmul_rn(a,b); }
__device__ __forceinline__ float fdiv32(float a, float b){ return __fdiv_rn(a,b); }

// ---- np-faithful per-edge force: f = Jx @ (p[e0]-p[e1]) ----
// numpy einsum 'eij,ej->ei' count=3 tail: switch fallthrough -> j DESCENDING (2,1,0).
__device__ __forceinline__ void edge_force(int2 e, int eidx,
                                           const float* __restrict__ pos,
                                           const float* __restrict__ rl,
                                           const float* __restrict__ p,
                                           float f[3]) {
    int i0 = 3 * e.x, i1 = 3 * e.y;
    float d[3], dh[3], dv[3];
    d[0] = fsub32(pos[i0 + 0], pos[i1 + 0]);
    d[1] = fsub32(pos[i0 + 1], pos[i1 + 1]);
    d[2] = fsub32(pos[i0 + 2], pos[i1 + 2]);
    // np.sum(d*d,-1): n=3 pairwise small branch = ascending sequential
    float ss = fadd32(fadd32(fmul32(d[0], d[0]), fmul32(d[1], d[1])), fmul32(d[2], d[2]));
    float l  = fadd32(__fsqrt_rn(ss), 1e-8f);
    dh[0] = fdiv32(d[0], l); dh[1] = fdiv32(d[1], l); dh[2] = fdiv32(d[2], l);
    float coef = fsub32(1.0f, fdiv32(rl[eidx], l));
    dv[0] = fsub32(p[i0 + 0], p[i1 + 0]);
    dv[1] = fsub32(p[i0 + 1], p[i1 + 1]);
    dv[2] = fsub32(p[i0 + 2], p[i1 + 2]);
    #pragma unroll
    for (int i = 0; i < 3; ++i) {
        float acc = 0.0f;
        #pragma unroll
        for (int j = 2; j >= 0; --j) {   // DESCENDING: numpy einsum tail order
            float dd = fmul32(dh[i], dh[j]);
            float t  = (i == j) ? fsub32(1.0f, dd) : fsub32(0.0f, dd);  // I3 - ddT
            float w  = fadd32(fmul32(coef, t), dd);   // coef*(I-ddT) + ddT
            float Jx = fmul32(-1000.0f, w);           // -KS * (...)
            acc = fadd32(acc, fmul32(Jx, dv[j]));
        }
        f[i] = acc;
    }
}

// ---- build: incidence CSR, deterministic, rebuilt every launch ----
__global__ void count_k(const int2* __restrict__ ed, int* __restrict__ cnt0,
                        int* __restrict__ cnt1, int ne) {
    int i = blockIdx.x * blockDim.x + threadIdx.x;
    if (i >= ne) return;
    int2 e = ed[i];
    atomicAdd(&cnt0[e.x], 1);
    atomicAdd(&cnt1[e.y], 1);
}

__global__ void scan_k(const int* __restrict__ cnt0, const int* __restrict__ cnt1,
                       int* __restrict__ segoff, int* __restrict__ split,
                       int* __restrict__ cur0, int* __restrict__ cur1, int nv) {
    __shared__ int lds[1024];
    int tid = threadIdx.x;
    int chunk = (nv + 1023) / 1024;
    int lo = tid * chunk;
    int hi = lo + chunk; if (hi > nv) hi = nv; if (lo > nv) lo = nv;
    int s = 0;
    for (int v = lo; v < hi; ++v) s += cnt0[v] + cnt1[v];
    lds[tid] = s;
    __syncthreads();
    for (int off = 1; off < 1024; off <<= 1) {
        int t = (tid >= off) ? lds[tid - off] : 0;
        __syncthreads();
        lds[tid] += t;
        __syncthreads();
    }
    int run = lds[tid] - s;  // exclusive
    for (int v = lo; v < hi; ++v) {
        int c0 = cnt0[v], c1 = cnt1[v];
        segoff[v] = run;
        split[v]  = run + c0;
        cur0[v]   = run;
        cur1[v]   = run + c0;
        run += c0 + c1;
    }
    if (tid == 1023) segoff[nv] = lds[1023];
}

__global__ void fill_k(const int2* __restrict__ ed, int* __restrict__ cur0,
                       int* __restrict__ cur1, int* __restrict__ inc, int ne) {
    int i = blockIdx.x * blockDim.x + threadIdx.x;
    if (i >= ne) return;
    int2 e = ed[i];
    int s0 = atomicAdd(&cur0[e.x], 1); inc[s0] = i;
    int s1 = atomicAdd(&cur1[e.y], 1); inc[s1] = i;
}

__global__ void sort_k(int* __restrict__ inc, const int* __restrict__ segoff,
                       const int* __restrict__ split, int nv) {
    int v = blockIdx.x * blockDim.x + threadIdx.x;
    if (v >= nv) return;
    int lo = segoff[v], mid = split[v], hi = segoff[v + 1];
    for (int a = lo + 1; a < mid; ++a) {
        int key = inc[a]; int b = a - 1;
        while (b >= lo && inc[b] > key) { inc[b + 1] = inc[b]; --b; }
        inc[b + 1] = key;
    }
    for (int a = mid + 1; a < hi; ++a) {
        int key = inc[a]; int b = a - 1;
        while (b >= mid && inc[b] > key) { inc[b + 1] = inc[b]; --b; }
        inc[b + 1] = key;
    }
}

// ---- CG kernels ----
// init: x=0, r=p=b, prod = b*b (for rs0 chain)
__global__ void init_k(const float* __restrict__ rhs, float* __restrict__ x,
                       float* __restrict__ r, float* __restrict__ p,
                       float* __restrict__ prod, int n) {
    int j = blockIdx.x * blockDim.x + threadIdx.x;
    if (j >= n) return;
    float b = rhs[j];
    x[j] = 0.0f; r[j] = b; p[j] = b;
    prod[j] = fmul32(b, b);
}

// matvec per vertex (np.add.at order) + prod = p*Ap (for pAp chain)
__global__ void mv_k(const int2* __restrict__ ed, const float* __restrict__ pos,
                     const float* __restrict__ rl, const float* __restrict__ p,
                     const float* __restrict__ mass, const int* __restrict__ inc,
                     const int* __restrict__ segoff, const int* __restrict__ split,
                     float* __restrict__ Ap, float* __restrict__ prod, int nv) {
    int v = blockIdx.x * blockDim.x + threadIdx.x;
    if (v >= nv) return;
    int lo = segoff[v], mid = split[v], hi = segoff[v + 1];
    float a0 = 0.0f, a1 = 0.0f, a2 = 0.0f;
    for (int k = lo; k < mid; ++k) {
        int e = inc[k]; float f[3];
        edge_force(ed[e], e, pos, rl, p, f);
        a0 = fadd32(a0, f[0]); a1 = fadd32(a1, f[1]); a2 = fadd32(a2, f[2]);
    }
    for (int k = mid; k < hi; ++k) {
        int e = inc[k]; float f[3];
        edge_force(ed[e], e, pos, rl, p, f);
        a0 = fadd32(a0, -f[0]); a1 = fadd32(a1, -f[1]); a2 = fadd32(a2, -f[2]);
    }
    const float h2 = (float)(0.01 * 0.01);   // f32(H*H): f64 product, one cast
    int j = 3 * v; float m = mass[v];
    float p0 = p[j], p1 = p[j + 1], p2 = p[j + 2];
    float A0 = fsub32(fmul32(m, p0), fmul32(h2, a0));
    float A1 = fsub32(fmul32(m, p1), fmul32(h2, a1));
    float A2 = fsub32(fmul32(m, p2), fmul32(h2, a2));
    Ap[j + 0] = A0; Ap[j + 1] = A1; Ap[j + 2] = A2;
    prod[j + 0] = fmul32(p0, A0);
    prod[j + 1] = fmul32(p1, A1);
    prod[j + 2] = fmul32(p2, A2);
}

#define ACC4(v) { s = fadd32(s, (v).x); s = fadd32(s, (v).y); \
                  s = fadd32(s, (v).z); s = fadd32(s, (v).w); }

// Serial sequential-f32 add chain (numpy no-CBLAS FLOAT_dot order).
// Producer threads stage tile t+1 HBM->LDS while thread 0 chains tile t.
// Thread 0 additionally register-double-buffers: ds_reads for group i+1
// issue BEFORE the 32 dependent fadds of group i -> LDS latency hidden,
// chain runs at dependent-fadd latency. Values/order bit-identical to numpy.
__global__ void chain_k(const float* __restrict__ prod, float* __restrict__ out, int n) {
    __shared__ float buf[2][TILE];
    int tid = threadIdx.x;
    int ntiles = (n + TILE - 1) / TILE;
    {
        int lim = (TILE < n) ? TILE : n;
        for (int i = tid; i < lim; i += CHAIN_TB) buf[0][i] = prod[i];
    }
    __syncthreads();
    float s = 0.0f;
    for (int t = 0; t < ntiles; ++t) {
        if (t + 1 < ntiles) {                 // stage next tile while chaining
            int base = (t + 1) * TILE;
            int lim = n - base; if (lim > TILE) lim = TILE;
            float* dst = buf[(t + 1) & 1];
            for (int i = tid; i < lim; i += CHAIN_TB) dst[i] = prod[base + i];
        }
        if (tid == 0) {
            const float* b = buf[t & 1];
            int cnt = n - t * TILE; if (cnt > TILE) cnt = TILE;
            const float4* b4 = (const float4*)b;
            int c4 = cnt >> 2;
            int i = 0;
            if (c4 >= 8) {
                float4 cur[8];
                #pragma unroll
                for (int k = 0; k < 8; ++k) cur[k] = b4[k];
                for (; i + 8 <= c4; i += 8) {
                    float4 nxt[8];
                    bool more = (i + 16 <= c4);
                    if (more) {
                        #pragma unroll
                        for (int k = 0; k < 8; ++k) nxt[k] = b4[i + 8 + k];
                    }
                    ACC4(cur[0]) ACC4(cur[1]) ACC4(cur[2]) ACC4(cur[3])
                    ACC4(cur[4]) ACC4(cur[5]) ACC4(cur[6]) ACC4(cur[7])
                    if (more) {
                        #pragma unroll
                        for (int k = 0; k < 8; ++k) cur[k] = nxt[k];
                    }
                }
            }
            for (; i < c4; ++i) { float4 v = b4[i]; ACC4(v) }
            for (int k = c4 << 2; k < cnt; ++k) s = fadd32(s, b[k]);
        }
        __syncthreads();   // tile t+1 staged AND thread0 done with buf[t&1]
    }
    if (tid == 0) out[0] = s;
}

// x += alpha p ; r -= alpha Ap ; prod = r_new*r_new (for rs chain)
// numpy 1.x scalar-scalar promotion: alpha = f32( (f64)rs / ((f64)pAp + 1e-8) )
__global__ void xr_k(float* __restrict__ x, float* __restrict__ r,
                     const float* __restrict__ p, const float* __restrict__ Ap,
                     float* __restrict__ prod, const float* __restrict__ scal,
                     int it, int n) {
    int j = blockIdx.x * blockDim.x + threadIdx.x;
    if (j >= n) return;
    float alpha = (float)((double)scal[it] / ((double)scal[PAP_OFF + it] + 1e-8));
    x[j] = fadd32(x[j], fmul32(alpha, p[j]));
    float rn = fsub32(r[j], fmul32(alpha, Ap[j]));
    r[j] = rn;
    prod[j] = fmul32(rn, rn);
}

__global__ void p_k(const float* __restrict__ r, float* __restrict__ p,
                    const float* __restrict__ scal, int it, int n) {
    int j = blockIdx.x * blockDim.x + threadIdx.x;
    if (j >= n) return;
    float beta = (float)((double)scal[it + 1] / ((double)scal[it] + 1e-8));
    p[j] = fadd32(r[j], fmul32(beta, p[j]));
}

extern "C" void kernel_launch(void* const* d_in, const int* in_sizes, int n_in,
                              void* d_out, int out_size, void* d_ws, size_t ws_size,
                              hipStream_t stream) {
    const float* rhs  = (const float*)d_in[0];
    const float* pos  = (const float*)d_in[1];
    const float* mass = (const float*)d_in[2];
    const float* rl   = (const float*)d_in[3];
    const int2*  ed   = (const int2*)d_in[4];
    float* x = (float*)d_out;

    int NV = in_sizes[0] / 3;
    int NE = in_sizes[3];
    int n3 = NV * 3;

    char* w = (char*)d_ws;
    float* r    = (float*)w;  w += (size_t)n3 * sizeof(float);
    float* p    = (float*)w;  w += (size_t)n3 * sizeof(float);
    float* Ap   = (float*)w;  w += (size_t)n3 * sizeof(float);
    float* prod = (float*)w;  w += (size_t)n3 * sizeof(float);
    int*   inc  = (int*)w;    w += (size_t)2 * NE * sizeof(int);
    int*   cnt0 = (int*)w;    w += (size_t)NV * sizeof(int);
    int*   cnt1 = (int*)w;    w += (size_t)NV * sizeof(int);
    int*   segoff = (int*)w;  w += (size_t)(NV + 1) * sizeof(int);
    int*   split  = (int*)w;  w += (size_t)NV * sizeof(int);
    int*   cur0   = (int*)w;  w += (size_t)NV * sizeof(int);
    int*   cur1   = (int*)w;  w += (size_t)NV * sizeof(int);
    float* scal   = (float*)w;

    hipMemsetAsync(cnt0, 0, (size_t)2 * NV * sizeof(int), stream);  // cnt0+cnt1 adjacent

    const int tb = 256;
    int gE = (NE + tb - 1) / tb;
    int gV = (NV + tb - 1) / tb;
    int g3 = (n3 + tb - 1) / tb;

    count_k<<<gE, tb, 0, stream>>>(ed, cnt0, cnt1, NE);
    scan_k<<<1, 1024, 0, stream>>>(cnt0, cnt1, segoff, split, cur0, cur1, NV);
    fill_k<<<gE, tb, 0, stream>>>(ed, cur0, cur1, inc, NE);
    sort_k<<<gV, tb, 0, stream>>>(inc, segoff, split, NV);

    init_k<<<g3, tb, 0, stream>>>(rhs, x, r, p, prod, n3);
    chain_k<<<1, CHAIN_TB, 0, stream>>>(prod, &scal[0], n3);   // rs0 = vdot(b,b)

    for (int it = 0; it < CG_ITERS; ++it) {
        mv_k<<<gV, tb, 0, stream>>>(ed, pos, rl, p, mass, inc, segoff, split, Ap, prod, NV);
        chain_k<<<1, CHAIN_TB, 0, stream>>>(prod, &scal[PAP_OFF + it], n3);
        xr_k<<<g3, tb, 0, stream>>>(x, r, p, Ap, prod, scal, it, n3);
        if (it + 1 < CG_ITERS) {   // scal[30] and final p never affect x
            chain_k<<<1, CHAIN_TB, 0, stream>>>(prod, &scal[it + 1], n3);
            p_k<<<g3, tb, 0, stream>>>(r, p, scal, it, n3);
        }
    }
}

// Round 13
// 143146.619 us; speedup vs baseline: 3.3405x; 3.3405x over previous
//
#include <hip/hip_runtime.h>

#define CG_ITERS 30
#define PAP_OFF 32   // scal[0..30] = rs_i (f32) ; scal[32+it] = pAp_it (f32)
#define TILE 8192
#define CHAIN_TB 256

__device__ __forceinline__ float fadd32(float a, float b){ return __fadd_rn(a,b); }
__device__ __forceinline__ float fsub32(float a, float b){ return __fsub_rn(a,b); }
__device__ __forceinline__ float fmul32(float a, float b){ return __fmul_rn(a,b); }
__device__ __forceinline__ float fdiv32(float a, float b){ return __fdiv_rn(a,b); }

// ---- np-faithful per-edge force: f = Jx @ (p[e0]-p[e1]) ----
// numpy einsum 'eij,ej->ei' count=3 tail: switch fallthrough -> j DESCENDING (2,1,0).
__device__ __forceinline__ void edge_force(int2 e, int eidx,
                                           const float* __restrict__ pos,
                                           const float* __restrict__ rl,
                                           const float* __restrict__ p,
                                           float f[3]) {
    int i0 = 3 * e.x, i1 = 3 * e.y;
    float d[3], dh[3], dv[3];
    d[0] = fsub32(pos[i0 + 0], pos[i1 + 0]);
    d[1] = fsub32(pos[i0 + 1], pos[i1 + 1]);
    d[2] = fsub32(pos[i0 + 2], pos[i1 + 2]);
    // np.sum(d*d,-1): n=3 pairwise small branch = ascending sequential
    float ss = fadd32(fadd32(fmul32(d[0], d[0]), fmul32(d[1], d[1])), fmul32(d[2], d[2]));
    float l  = fadd32(__fsqrt_rn(ss), 1e-8f);
    dh[0] = fdiv32(d[0], l); dh[1] = fdiv32(d[1], l); dh[2] = fdiv32(d[2], l);
    float coef = fsub32(1.0f, fdiv32(rl[eidx], l));
    dv[0] = fsub32(p[i0 + 0], p[i1 + 0]);
    dv[1] = fsub32(p[i0 + 1], p[i1 + 1]);
    dv[2] = fsub32(p[i0 + 2], p[i1 + 2]);
    #pragma unroll
    for (int i = 0; i < 3; ++i) {
        float acc = 0.0f;
        #pragma unroll
        for (int j = 2; j >= 0; --j) {   // DESCENDING: numpy einsum tail order
            float dd = fmul32(dh[i], dh[j]);
            float t  = (i == j) ? fsub32(1.0f, dd) : fsub32(0.0f, dd);  // I3 - ddT
            float w  = fadd32(fmul32(coef, t), dd);   // coef*(I-ddT) + ddT
            float Jx = fmul32(-1000.0f, w);           // -KS * (...)
            acc = fadd32(acc, fmul32(Jx, dv[j]));
        }
        f[i] = acc;
    }
}

// ---- build: incidence CSR, deterministic, rebuilt every launch ----
__global__ void count_k(const int2* __restrict__ ed, int* __restrict__ cnt0,
                        int* __restrict__ cnt1, int ne) {
    int i = blockIdx.x * blockDim.x + threadIdx.x;
    if (i >= ne) return;
    int2 e = ed[i];
    atomicAdd(&cnt0[e.x], 1);
    atomicAdd(&cnt1[e.y], 1);
}

__global__ void scan_k(const int* __restrict__ cnt0, const int* __restrict__ cnt1,
                       int* __restrict__ segoff, int* __restrict__ split,
                       int* __restrict__ cur0, int* __restrict__ cur1, int nv) {
    __shared__ int lds[1024];
    int tid = threadIdx.x;
    int chunk = (nv + 1023) / 1024;
    int lo = tid * chunk;
    int hi = lo + chunk; if (hi > nv) hi = nv; if (lo > nv) lo = nv;
    int s = 0;
    for (int v = lo; v < hi; ++v) s += cnt0[v] + cnt1[v];
    lds[tid] = s;
    __syncthreads();
    for (int off = 1; off < 1024; off <<= 1) {
        int t = (tid >= off) ? lds[tid - off] : 0;
        __syncthreads();
        lds[tid] += t;
        __syncthreads();
    }
    int run = lds[tid] - s;  // exclusive
    for (int v = lo; v < hi; ++v) {
        int c0 = cnt0[v], c1 = cnt1[v];
        segoff[v] = run;
        split[v]  = run + c0;
        cur0[v]   = run;
        cur1[v]   = run + c0;
        run += c0 + c1;
    }
    if (tid == 1023) segoff[nv] = lds[1023];
}

__global__ void fill_k(const int2* __restrict__ ed, int* __restrict__ cur0,
                       int* __restrict__ cur1, int* __restrict__ inc, int ne) {
    int i = blockIdx.x * blockDim.x + threadIdx.x;
    if (i >= ne) return;
    int2 e = ed[i];
    int s0 = atomicAdd(&cur0[e.x], 1); inc[s0] = i;
    int s1 = atomicAdd(&cur1[e.y], 1); inc[s1] = i;
}

__global__ void sort_k(int* __restrict__ inc, const int* __restrict__ segoff,
                       const int* __restrict__ split, int nv) {
    int v = blockIdx.x * blockDim.x + threadIdx.x;
    if (v >= nv) return;
    int lo = segoff[v], mid = split[v], hi = segoff[v + 1];
    for (int a = lo + 1; a < mid; ++a) {
        int key = inc[a]; int b = a - 1;
        while (b >= lo && inc[b] > key) { inc[b + 1] = inc[b]; --b; }
        inc[b + 1] = key;
    }
    for (int a = mid + 1; a < hi; ++a) {
        int key = inc[a]; int b = a - 1;
        while (b >= mid && inc[b] > key) { inc[b + 1] = inc[b]; --b; }
        inc[b + 1] = key;
    }
}

// ---- CG kernels ----
// init: x=0, r=p=b, prod = b*b (for rs0 chain)
__global__ void init_k(const float* __restrict__ rhs, float* __restrict__ x,
                       float* __restrict__ r, float* __restrict__ p,
                       float* __restrict__ prod, int n) {
    int j = blockIdx.x * blockDim.x + threadIdx.x;
    if (j >= n) return;
    float b = rhs[j];
    x[j] = 0.0f; r[j] = b; p[j] = b;
    prod[j] = fmul32(b, b);
}

// matvec per vertex (np.add.at order) + prod = p*Ap (for pAp chain)
__global__ void mv_k(const int2* __restrict__ ed, const float* __restrict__ pos,
                     const float* __restrict__ rl, const float* __restrict__ p,
                     const float* __restrict__ mass, const int* __restrict__ inc,
                     const int* __restrict__ segoff, const int* __restrict__ split,
                     float* __restrict__ Ap, float* __restrict__ prod, int nv) {
    int v = blockIdx.x * blockDim.x + threadIdx.x;
    if (v >= nv) return;
    int lo = segoff[v], mid = split[v], hi = segoff[v + 1];
    float a0 = 0.0f, a1 = 0.0f, a2 = 0.0f;
    for (int k = lo; k < mid; ++k) {
        int e = inc[k]; float f[3];
        edge_force(ed[e], e, pos, rl, p, f);
        a0 = fadd32(a0, f[0]); a1 = fadd32(a1, f[1]); a2 = fadd32(a2, f[2]);
    }
    for (int k = mid; k < hi; ++k) {
        int e = inc[k]; float f[3];
        edge_force(ed[e], e, pos, rl, p, f);
        a0 = fadd32(a0, -f[0]); a1 = fadd32(a1, -f[1]); a2 = fadd32(a2, -f[2]);
    }
    const float h2 = (float)(0.01 * 0.01);   // f32(H*H): f64 product, one cast
    int j = 3 * v; float m = mass[v];
    float p0 = p[j], p1 = p[j + 1], p2 = p[j + 2];
    float A0 = fsub32(fmul32(m, p0), fmul32(h2, a0));
    float A1 = fsub32(fmul32(m, p1), fmul32(h2, a1));
    float A2 = fsub32(fmul32(m, p2), fmul32(h2, a2));
    Ap[j + 0] = A0; Ap[j + 1] = A1; Ap[j + 2] = A2;
    prod[j + 0] = fmul32(p0, A0);
    prod[j + 1] = fmul32(p1, A1);
    prod[j + 2] = fmul32(p2, A2);
}

#define ACC4(v) { s = fadd32(s, (v).x); s = fadd32(s, (v).y); \
                  s = fadd32(s, (v).z); s = fadd32(s, (v).w); }
#define LD8(p4, base, a,b,c,d,e,f,g,h) { a=(p4)[(base)+0]; b=(p4)[(base)+1]; \
    c=(p4)[(base)+2]; d=(p4)[(base)+3]; e=(p4)[(base)+4]; f=(p4)[(base)+5]; \
    g=(p4)[(base)+6]; h=(p4)[(base)+7]; }

// Serial sequential-f32 add chain (numpy no-CBLAS FLOAT_dot order).
// Producer threads stage tile t+1 HBM->LDS while thread 0 chains tile t.
// Thread 0 register-prefetches group i+1 (8x ds_read_b128, named regs — no
// arrays, no spill) BEFORE the 32 dependent fadds of group i.
// __launch_bounds__(256,1): lift the 64-VGPR occupancy cap that spilled R12.
// Values and order bit-identical to numpy: float sum=0; for i: sum+=prod[i].
__global__ void __launch_bounds__(CHAIN_TB, 1)
chain_k(const float* __restrict__ prod, float* __restrict__ out, int n) {
    __shared__ float buf[2][TILE];
    int tid = threadIdx.x;
    int ntiles = (n + TILE - 1) / TILE;
    {
        int lim = (TILE < n) ? TILE : n;
        for (int i = tid; i < lim; i += CHAIN_TB) buf[0][i] = prod[i];
    }
    __syncthreads();
    float s = 0.0f;
    for (int t = 0; t < ntiles; ++t) {
        if (t + 1 < ntiles) {                 // stage next tile while chaining
            int base = (t + 1) * TILE;
            int lim = n - base; if (lim > TILE) lim = TILE;
            float* dst = buf[(t + 1) & 1];
            for (int i = tid; i < lim; i += CHAIN_TB) dst[i] = prod[base + i];
        }
        if (tid == 0) {
            const float* b = buf[t & 1];
            int cnt = n - t * TILE; if (cnt > TILE) cnt = TILE;
            const float4* b4 = (const float4*)b;
            int c4 = cnt >> 2;
            int i = 0;
            if (c4 >= 8) {
                float4 c0, c1, c2, c3, c4v, c5, c6, c7;
                LD8(b4, 0, c0, c1, c2, c3, c4v, c5, c6, c7)
                for (; i + 16 <= c4; i += 8) {
                    float4 n0, n1, n2, n3, n4, n5, n6, n7;
                    LD8(b4, i + 8, n0, n1, n2, n3, n4, n5, n6, n7)
                    ACC4(c0) ACC4(c1) ACC4(c2) ACC4(c3)
                    ACC4(c4v) ACC4(c5) ACC4(c6) ACC4(c7)
                    c0 = n0; c1 = n1; c2 = n2; c3 = n3;
                    c4v = n4; c5 = n5; c6 = n6; c7 = n7;
                }
                ACC4(c0) ACC4(c1) ACC4(c2) ACC4(c3)
                ACC4(c4v) ACC4(c5) ACC4(c6) ACC4(c7)
                i += 8;
            }
            for (; i < c4; ++i) { float4 v = b4[i]; ACC4(v) }
            for (int k = c4 << 2; k < cnt; ++k) s = fadd32(s, b[k]);
        }
        __syncthreads();   // tile t+1 staged AND thread0 done with buf[t&1]
    }
    if (tid == 0) out[0] = s;
}

// x += alpha p ; r -= alpha Ap ; prod = r_new*r_new (for rs chain)
// numpy 1.x scalar-scalar promotion: alpha = f32( (f64)rs / ((f64)pAp + 1e-8) )
__global__ void xr_k(float* __restrict__ x, float* __restrict__ r,
                     const float* __restrict__ p, const float* __restrict__ Ap,
                     float* __restrict__ prod, const float* __restrict__ scal,
                     int it, int n) {
    int j = blockIdx.x * blockDim.x + threadIdx.x;
    if (j >= n) return;
    float alpha = (float)((double)scal[it] / ((double)scal[PAP_OFF + it] + 1e-8));
    x[j] = fadd32(x[j], fmul32(alpha, p[j]));
    float rn = fsub32(r[j], fmul32(alpha, Ap[j]));
    r[j] = rn;
    prod[j] = fmul32(rn, rn);
}

__global__ void p_k(const float* __restrict__ r, float* __restrict__ p,
                    const float* __restrict__ scal, int it, int n) {
    int j = blockIdx.x * blockDim.x + threadIdx.x;
    if (j >= n) return;
    float beta = (float)((double)scal[it + 1] / ((double)scal[it] + 1e-8));
    p[j] = fadd32(r[j], fmul32(beta, p[j]));
}

extern "C" void kernel_launch(void* const* d_in, const int* in_sizes, int n_in,
                              void* d_out, int out_size, void* d_ws, size_t ws_size,
                              hipStream_t stream) {
    const float* rhs  = (const float*)d_in[0];
    const float* pos  = (const float*)d_in[1];
    const float* mass = (const float*)d_in[2];
    const float* rl   = (const float*)d_in[3];
    const int2*  ed   = (const int2*)d_in[4];
    float* x = (float*)d_out;

    int NV = in_sizes[0] / 3;
    int NE = in_sizes[3];
    int n3 = NV * 3;

    char* w = (char*)d_ws;
    float* r    = (float*)w;  w += (size_t)n3 * sizeof(float);
    float* p    = (float*)w;  w += (size_t)n3 * sizeof(float);
    float* Ap   = (float*)w;  w += (size_t)n3 * sizeof(float);
    float* prod = (float*)w;  w += (size_t)n3 * sizeof(float);
    int*   inc  = (int*)w;    w += (size_t)2 * NE * sizeof(int);
    int*   cnt0 = (int*)w;    w += (size_t)NV * sizeof(int);
    int*   cnt1 = (int*)w;    w += (size_t)NV * sizeof(int);
    int*   segoff = (int*)w;  w += (size_t)(NV + 1) * sizeof(int);
    int*   split  = (int*)w;  w += (size_t)NV * sizeof(int);
    int*   cur0   = (int*)w;  w += (size_t)NV * sizeof(int);
    int*   cur1   = (int*)w;  w += (size_t)NV * sizeof(int);
    float* scal   = (float*)w;

    hipMemsetAsync(cnt0, 0, (size_t)2 * NV * sizeof(int), stream);  // cnt0+cnt1 adjacent

    const int tb = 256;
    int gE = (NE + tb - 1) / tb;
    int gV = (NV + tb - 1) / tb;
    int g3 = (n3 + tb - 1) / tb;

    count_k<<<gE, tb, 0, stream>>>(ed, cnt0, cnt1, NE);
    scan_k<<<1, 1024, 0, stream>>>(cnt0, cnt1, segoff, split, cur0, cur1, NV);
    fill_k<<<gE, tb, 0, stream>>>(ed, cur0, cur1, inc, NE);
    sort_k<<<gV, tb, 0, stream>>>(inc, segoff, split, NV);

    init_k<<<g3, tb, 0, stream>>>(rhs, x, r, p, prod, n3);
    chain_k<<<1, CHAIN_TB, 0, stream>>>(prod, &scal[0], n3);   // rs0 = vdot(b,b)

    for (int it = 0; it < CG_ITERS; ++it) {
        mv_k<<<gV, tb, 0, stream>>>(ed, pos, rl, p, mass, inc, segoff, split, Ap, prod, NV);
        chain_k<<<1, CHAIN_TB, 0, stream>>>(prod, &scal[PAP_OFF + it], n3);
        xr_k<<<g3, tb, 0, stream>>>(x, r, p, Ap, prod, scal, it, n3);
        if (it + 1 < CG_ITERS) {   // scal[30] and final p never affect x
            chain_k<<<1, CHAIN_TB, 0, stream>>>(prod, &scal[it + 1], n3);
            p_k<<<g3, tb, 0, stream>>>(r, p, scal, it, n3);
        }
    }
}

// Round 14
// 137440.112 us; speedup vs baseline: 3.4792x; 1.0415x over previous
//
#include <hip/hip_runtime.h>

#define CG_ITERS 30
#define PAP_OFF 32   // scal[0..30] = rs_i (f32) ; scal[32+it] = pAp_it (f32)
#define TILE 8192
#define CHAIN_TB 256

__device__ __forceinline__ float fadd32(float a, float b){ return __fadd_rn(a,b); }
__device__ __forceinline__ float fsub32(float a, float b){ return __fsub_rn(a,b); }
__device__ __forceinline__ float fmul32(float a, float b){ return __fmul_rn(a,b); }
__device__ __forceinline__ float fdiv32(float a, float b){ return __fdiv_rn(a,b); }

// ---- np-faithful per-edge force: f = Jx @ (p[e0]-p[e1]) ----
// numpy einsum 'eij,ej->ei' count=3 tail: switch fallthrough -> j DESCENDING (2,1,0).
__device__ __forceinline__ void edge_force(int2 e, int eidx,
                                           const float* __restrict__ pos,
                                           const float* __restrict__ rl,
                                           const float* __restrict__ p,
                                           float f[3]) {
    int i0 = 3 * e.x, i1 = 3 * e.y;
    float d[3], dh[3], dv[3];
    d[0] = fsub32(pos[i0 + 0], pos[i1 + 0]);
    d[1] = fsub32(pos[i0 + 1], pos[i1 + 1]);
    d[2] = fsub32(pos[i0 + 2], pos[i1 + 2]);
    float ss = fadd32(fadd32(fmul32(d[0], d[0]), fmul32(d[1], d[1])), fmul32(d[2], d[2]));
    float l  = fadd32(__fsqrt_rn(ss), 1e-8f);
    dh[0] = fdiv32(d[0], l); dh[1] = fdiv32(d[1], l); dh[2] = fdiv32(d[2], l);
    float coef = fsub32(1.0f, fdiv32(rl[eidx], l));
    dv[0] = fsub32(p[i0 + 0], p[i1 + 0]);
    dv[1] = fsub32(p[i0 + 1], p[i1 + 1]);
    dv[2] = fsub32(p[i0 + 2], p[i1 + 2]);
    #pragma unroll
    for (int i = 0; i < 3; ++i) {
        float acc = 0.0f;
        #pragma unroll
        for (int j = 2; j >= 0; --j) {   // DESCENDING: numpy einsum tail order
            float dd = fmul32(dh[i], dh[j]);
            float t  = (i == j) ? fsub32(1.0f, dd) : fsub32(0.0f, dd);  // I3 - ddT
            float w  = fadd32(fmul32(coef, t), dd);   // coef*(I-ddT) + ddT
            float Jx = fmul32(-1000.0f, w);           // -KS * (...)
            acc = fadd32(acc, fmul32(Jx, dv[j]));
        }
        f[i] = acc;
    }
}

// ---- build: incidence CSR, deterministic, rebuilt every launch ----
__global__ void count_k(const int2* __restrict__ ed, int* __restrict__ cnt0,
                        int* __restrict__ cnt1, int ne) {
    int i = blockIdx.x * blockDim.x + threadIdx.x;
    if (i >= ne) return;
    int2 e = ed[i];
    atomicAdd(&cnt0[e.x], 1);
    atomicAdd(&cnt1[e.y], 1);
}

__global__ void scan_k(const int* __restrict__ cnt0, const int* __restrict__ cnt1,
                       int* __restrict__ segoff, int* __restrict__ split,
                       int* __restrict__ cur0, int* __restrict__ cur1, int nv) {
    __shared__ int lds[1024];
    int tid = threadIdx.x;
    int chunk = (nv + 1023) / 1024;
    int lo = tid * chunk;
    int hi = lo + chunk; if (hi > nv) hi = nv; if (lo > nv) lo = nv;
    int s = 0;
    for (int v = lo; v < hi; ++v) s += cnt0[v] + cnt1[v];
    lds[tid] = s;
    __syncthreads();
    for (int off = 1; off < 1024; off <<= 1) {
        int t = (tid >= off) ? lds[tid - off] : 0;
        __syncthreads();
        lds[tid] += t;
        __syncthreads();
    }
    int run = lds[tid] - s;  // exclusive
    for (int v = lo; v < hi; ++v) {
        int c0 = cnt0[v], c1 = cnt1[v];
        segoff[v] = run;
        split[v]  = run + c0;
        cur0[v]   = run;
        cur1[v]   = run + c0;
        run += c0 + c1;
    }
    if (tid == 1023) segoff[nv] = lds[1023];
}

__global__ void fill_k(const int2* __restrict__ ed, int* __restrict__ cur0,
                       int* __restrict__ cur1, int* __restrict__ inc, int ne) {
    int i = blockIdx.x * blockDim.x + threadIdx.x;
    if (i >= ne) return;
    int2 e = ed[i];
    int s0 = atomicAdd(&cur0[e.x], 1); inc[s0] = i;
    int s1 = atomicAdd(&cur1[e.y], 1); inc[s1] = i;
}

__global__ void sort_k(int* __restrict__ inc, const int* __restrict__ segoff,
                       const int* __restrict__ split, int nv) {
    int v = blockIdx.x * blockDim.x + threadIdx.x;
    if (v >= nv) return;
    int lo = segoff[v], mid = split[v], hi = segoff[v + 1];
    for (int a = lo + 1; a < mid; ++a) {
        int key = inc[a]; int b = a - 1;
        while (b >= lo && inc[b] > key) { inc[b + 1] = inc[b]; --b; }
        inc[b + 1] = key;
    }
    for (int a = mid + 1; a < hi; ++a) {
        int key = inc[a]; int b = a - 1;
        while (b >= mid && inc[b] > key) { inc[b + 1] = inc[b]; --b; }
        inc[b + 1] = key;
    }
}

// ---- CG kernels ----
__global__ void init_k(const float* __restrict__ rhs, float* __restrict__ x,
                       float* __restrict__ r, float* __restrict__ p,
                       float* __restrict__ prod, int n) {
    int j = blockIdx.x * blockDim.x + threadIdx.x;
    if (j >= n) return;
    float b = rhs[j];
    x[j] = 0.0f; r[j] = b; p[j] = b;
    prod[j] = fmul32(b, b);
}

// matvec per vertex (np.add.at order) + prod = p*Ap (for pAp chain)
__global__ void mv_k(const int2* __restrict__ ed, const float* __restrict__ pos,
                     const float* __restrict__ rl, const float* __restrict__ p,
                     const float* __restrict__ mass, const int* __restrict__ inc,
                     const int* __restrict__ segoff, const int* __restrict__ split,
                     float* __restrict__ Ap, float* __restrict__ prod, int nv) {
    int v = blockIdx.x * blockDim.x + threadIdx.x;
    if (v >= nv) return;
    int lo = segoff[v], mid = split[v], hi = segoff[v + 1];
    float a0 = 0.0f, a1 = 0.0f, a2 = 0.0f;
    for (int k = lo; k < mid; ++k) {
        int e = inc[k]; float f[3];
        edge_force(ed[e], e, pos, rl, p, f);
        a0 = fadd32(a0, f[0]); a1 = fadd32(a1, f[1]); a2 = fadd32(a2, f[2]);
    }
    for (int k = mid; k < hi; ++k) {
        int e = inc[k]; float f[3];
        edge_force(ed[e], e, pos, rl, p, f);
        a0 = fadd32(a0, -f[0]); a1 = fadd32(a1, -f[1]); a2 = fadd32(a2, -f[2]);
    }
    const float h2 = (float)(0.01 * 0.01);   // f32(H*H): f64 product, one cast
    int j = 3 * v; float m = mass[v];
    float p0 = p[j], p1 = p[j + 1], p2 = p[j + 2];
    float A0 = fsub32(fmul32(m, p0), fmul32(h2, a0));
    float A1 = fsub32(fmul32(m, p1), fmul32(h2, a1));
    float A2 = fsub32(fmul32(m, p2), fmul32(h2, a2));
    Ap[j + 0] = A0; Ap[j + 1] = A1; Ap[j + 2] = A2;
    prod[j + 0] = fmul32(p0, A0);
    prod[j + 1] = fmul32(p1, A1);
    prod[j + 2] = fmul32(p2, A2);
}

#define ACC4(v) { s = fadd32(s, (v).x); s = fadd32(s, (v).y); \
                  s = fadd32(s, (v).z); s = fadd32(s, (v).w); }
#define G8_DECL(P) float4 P##0, P##1, P##2, P##3, P##4, P##5, P##6, P##7;
#define G8_LOAD(P, b4, base) { P##0=(b4)[(base)+0]; P##1=(b4)[(base)+1]; \
    P##2=(b4)[(base)+2]; P##3=(b4)[(base)+3]; P##4=(b4)[(base)+4]; \
    P##5=(b4)[(base)+5]; P##6=(b4)[(base)+6]; P##7=(b4)[(base)+7]; }
#define G8_ACC(P) { ACC4(P##0) ACC4(P##1) ACC4(P##2) ACC4(P##3) \
                    ACC4(P##4) ACC4(P##5) ACC4(P##6) ACC4(P##7) }

// Serial sequential-f32 add chain (numpy no-CBLAS FLOAT_dot order).
// Producers stage tile t+1 HBM->LDS while thread 0 chains tile t.
// Thread 0: distance-2 register prefetch with 3-way rotation (A,B,C named
// groups, no copies): loads of group g+2 issue before the 32 fadds of group
// g -> each group's ds_reads get ~256 cyc of fadds to complete (>204 cyc
// needed). Values and order bit-identical to numpy.
__global__ void __launch_bounds__(CHAIN_TB, 1)
chain_k(const float* __restrict__ prod, float* __restrict__ out, int n) {
    __shared__ float buf[2][TILE];
    int tid = threadIdx.x;
    int ntiles = (n + TILE - 1) / TILE;
    {
        int lim = (TILE < n) ? TILE : n;
        for (int i = tid; i < lim; i += CHAIN_TB) buf[0][i] = prod[i];
    }
    __syncthreads();
    float s = 0.0f;
    for (int t = 0; t < ntiles; ++t) {
        if (t + 1 < ntiles) {                 // stage next tile while chaining
            int base = (t + 1) * TILE;
            int lim = n - base; if (lim > TILE) lim = TILE;
            float* dst = buf[(t + 1) & 1];
            for (int i = tid; i < lim; i += CHAIN_TB) dst[i] = prod[base + i];
        }
        if (tid == 0) {
            const float* b = buf[t & 1];
            int cnt = n - t * TILE; if (cnt > TILE) cnt = TILE;
            const float4* b4 = (const float4*)b;
            int c4 = cnt >> 2;      // float4 count
            int ng = c4 >> 3;       // groups of 8 float4 (32 floats)
            int g = 0;
            if (ng >= 5) {
                G8_DECL(A) G8_DECL(B) G8_DECL(C)
                G8_LOAD(A, b4, 0)
                G8_LOAD(B, b4, 8)
                for (; g + 5 <= ng; g += 3) {   // all prefetch bases <= ng-1
                    G8_LOAD(C, b4, (g + 2) << 3)  G8_ACC(A)
                    G8_LOAD(A, b4, (g + 3) << 3)  G8_ACC(B)
                    G8_LOAD(B, b4, (g + 4) << 3)  G8_ACC(C)
                }
                G8_ACC(A)   // group g
                G8_ACC(B)   // group g+1   (rem groups = 2..4, A/B valid)
                g += 2;
            }
            for (; g < ng; ++g) {   // <=2 exposed groups per tile
                G8_DECL(D)
                G8_LOAD(D, b4, g << 3)
                G8_ACC(D)
            }
            for (int i = ng << 3; i < c4; ++i) { float4 v = b4[i]; ACC4(v) }
            for (int k = c4 << 2; k < cnt; ++k) s = fadd32(s, b[k]);
        }
        __syncthreads();   // tile t+1 staged AND thread0 done with buf[t&1]
    }
    if (tid == 0) out[0] = s;
}

// x += alpha p ; r -= alpha Ap ; prod = r_new*r_new (for rs chain)
// numpy 1.x scalar-scalar promotion: alpha = f32( (f64)rs / ((f64)pAp + 1e-8) )
__global__ void xr_k(float* __restrict__ x, float* __restrict__ r,
                     const float* __restrict__ p, const float* __restrict__ Ap,
                     float* __restrict__ prod, const float* __restrict__ scal,
                     int it, int n) {
    int j = blockIdx.x * blockDim.x + threadIdx.x;
    if (j >= n) return;
    float alpha = (float)((double)scal[it] / ((double)scal[PAP_OFF + it] + 1e-8));
    x[j] = fadd32(x[j], fmul32(alpha, p[j]));
    float rn = fsub32(r[j], fmul32(alpha, Ap[j]));
    r[j] = rn;
    prod[j] = fmul32(rn, rn);
}

__global__ void p_k(const float* __restrict__ r, float* __restrict__ p,
                    const float* __restrict__ scal, int it, int n) {
    int j = blockIdx.x * blockDim.x + threadIdx.x;
    if (j >= n) return;
    float beta = (float)((double)scal[it + 1] / ((double)scal[it] + 1e-8));
    p[j] = fadd32(r[j], fmul32(beta, p[j]));
}

extern "C" void kernel_launch(void* const* d_in, const int* in_sizes, int n_in,
                              void* d_out, int out_size, void* d_ws, size_t ws_size,
                              hipStream_t stream) {
    const float* rhs  = (const float*)d_in[0];
    const float* pos  = (const float*)d_in[1];
    const float* mass = (const float*)d_in[2];
    const float* rl   = (const float*)d_in[3];
    const int2*  ed   = (const int2*)d_in[4];
    float* x = (float*)d_out;

    int NV = in_sizes[0] / 3;
    int NE = in_sizes[3];
    int n3 = NV * 3;

    char* w = (char*)d_ws;
    float* r    = (float*)w;  w += (size_t)n3 * sizeof(float);
    float* p    = (float*)w;  w += (size_t)n3 * sizeof(float);
    float* Ap   = (float*)w;  w += (size_t)n3 * sizeof(float);
    float* prod = (float*)w;  w += (size_t)n3 * sizeof(float);
    int*   inc  = (int*)w;    w += (size_t)2 * NE * sizeof(int);
    int*   cnt0 = (int*)w;    w += (size_t)NV * sizeof(int);
    int*   cnt1 = (int*)w;    w += (size_t)NV * sizeof(int);
    int*   segoff = (int*)w;  w += (size_t)(NV + 1) * sizeof(int);
    int*   split  = (int*)w;  w += (size_t)NV * sizeof(int);
    int*   cur0   = (int*)w;  w += (size_t)NV * sizeof(int);
    int*   cur1   = (int*)w;  w += (size_t)NV * sizeof(int);
    float* scal   = (float*)w;

    hipMemsetAsync(cnt0, 0, (size_t)2 * NV * sizeof(int), stream);  // cnt0+cnt1 adjacent

    const int tb = 256;
    int gE = (NE + tb - 1) / tb;
    int gV = (NV + tb - 1) / tb;
    int g3 = (n3 + tb - 1) / tb;

    count_k<<<gE, tb, 0, stream>>>(ed, cnt0, cnt1, NE);
    scan_k<<<1, 1024, 0, stream>>>(cnt0, cnt1, segoff, split, cur0, cur1, NV);
    fill_k<<<gE, tb, 0, stream>>>(ed, cur0, cur1, inc, NE);
    sort_k<<<gV, tb, 0, stream>>>(inc, segoff, split, NV);

    init_k<<<g3, tb, 0, stream>>>(rhs, x, r, p, prod, n3);
    chain_k<<<1, CHAIN_TB, 0, stream>>>(prod, &scal[0], n3);   // rs0 = vdot(b,b)

    for (int it = 0; it < CG_ITERS; ++it) {
        mv_k<<<gV, tb, 0, stream>>>(ed, pos, rl, p, mass, inc, segoff, split, Ap, prod, NV);
        chain_k<<<1, CHAIN_TB, 0, stream>>>(prod, &scal[PAP_OFF + it], n3);
        xr_k<<<g3, tb, 0, stream>>>(x, r, p, Ap, prod, scal, it, n3);
        if (it + 1 < CG_ITERS) {   // scal[30] and final p never affect x
            chain_k<<<1, CHAIN_TB, 0, stream>>>(prod, &scal[it + 1], n3);
            p_k<<<g3, tb, 0, stream>>>(r, p, scal, it, n3);
        }
    }
}

// Round 15
// 105753.027 us; speedup vs baseline: 4.5217x; 1.2996x over previous
//
#include <hip/hip_runtime.h>

#define CG_ITERS 30
#define PAP_OFF 32   // scal[0..30] = rs_i (f32) ; scal[32+it] = pAp_it (f32)
#define TILE 8192
#define CHAIN_TB 256

__device__ __forceinline__ float fadd32(float a, float b){ return __fadd_rn(a,b); }
__device__ __forceinline__ float fsub32(float a, float b){ return __fsub_rn(a,b); }
__device__ __forceinline__ float fmul32(float a, float b){ return __fmul_rn(a,b); }
__device__ __forceinline__ float fdiv32(float a, float b){ return __fdiv_rn(a,b); }

// ---- np-faithful per-edge force: f = Jx @ (p[e0]-p[e1]) ----
// numpy einsum 'eij,ej->ei' count=3 tail: switch fallthrough -> j DESCENDING (2,1,0).
__device__ __forceinline__ void edge_force(int2 e, int eidx,
                                           const float* __restrict__ pos,
                                           const float* __restrict__ rl,
                                           const float* __restrict__ p,
                                           float f[3]) {
    int i0 = 3 * e.x, i1 = 3 * e.y;
    float d[3], dh[3], dv[3];
    d[0] = fsub32(pos[i0 + 0], pos[i1 + 0]);
    d[1] = fsub32(pos[i0 + 1], pos[i1 + 1]);
    d[2] = fsub32(pos[i0 + 2], pos[i1 + 2]);
    float ss = fadd32(fadd32(fmul32(d[0], d[0]), fmul32(d[1], d[1])), fmul32(d[2], d[2]));
    float l  = fadd32(__fsqrt_rn(ss), 1e-8f);
    dh[0] = fdiv32(d[0], l); dh[1] = fdiv32(d[1], l); dh[2] = fdiv32(d[2], l);
    float coef = fsub32(1.0f, fdiv32(rl[eidx], l));
    dv[0] = fsub32(p[i0 + 0], p[i1 + 0]);
    dv[1] = fsub32(p[i0 + 1], p[i1 + 1]);
    dv[2] = fsub32(p[i0 + 2], p[i1 + 2]);
    #pragma unroll
    for (int i = 0; i < 3; ++i) {
        float acc = 0.0f;
        #pragma unroll
        for (int j = 2; j >= 0; --j) {   // DESCENDING: numpy einsum tail order
            float dd = fmul32(dh[i], dh[j]);
            float t  = (i == j) ? fsub32(1.0f, dd) : fsub32(0.0f, dd);  // I3 - ddT
            float w  = fadd32(fmul32(coef, t), dd);   // coef*(I-ddT) + ddT
            float Jx = fmul32(-1000.0f, w);           // -KS * (...)
            acc = fadd32(acc, fmul32(Jx, dv[j]));
        }
        f[i] = acc;
    }
}

// ---- build: incidence CSR, deterministic, rebuilt every launch ----
__global__ void count_k(const int2* __restrict__ ed, int* __restrict__ cnt0,
                        int* __restrict__ cnt1, int ne) {
    int i = blockIdx.x * blockDim.x + threadIdx.x;
    if (i >= ne) return;
    int2 e = ed[i];
    atomicAdd(&cnt0[e.x], 1);
    atomicAdd(&cnt1[e.y], 1);
}

__global__ void scan_k(const int* __restrict__ cnt0, const int* __restrict__ cnt1,
                       int* __restrict__ segoff, int* __restrict__ split,
                       int* __restrict__ cur0, int* __restrict__ cur1, int nv) {
    __shared__ int lds[1024];
    int tid = threadIdx.x;
    int chunk = (nv + 1023) / 1024;
    int lo = tid * chunk;
    int hi = lo + chunk; if (hi > nv) hi = nv; if (lo > nv) lo = nv;
    int s = 0;
    for (int v = lo; v < hi; ++v) s += cnt0[v] + cnt1[v];
    lds[tid] = s;
    __syncthreads();
    for (int off = 1; off < 1024; off <<= 1) {
        int t = (tid >= off) ? lds[tid - off] : 0;
        __syncthreads();
        lds[tid] += t;
        __syncthreads();
    }
    int run = lds[tid] - s;  // exclusive
    for (int v = lo; v < hi; ++v) {
        int c0 = cnt0[v], c1 = cnt1[v];
        segoff[v] = run;
        split[v]  = run + c0;
        cur0[v]   = run;
        cur1[v]   = run + c0;
        run += c0 + c1;
    }
    if (tid == 1023) segoff[nv] = lds[1023];
}

__global__ void fill_k(const int2* __restrict__ ed, int* __restrict__ cur0,
                       int* __restrict__ cur1, int* __restrict__ inc, int ne) {
    int i = blockIdx.x * blockDim.x + threadIdx.x;
    if (i >= ne) return;
    int2 e = ed[i];
    int s0 = atomicAdd(&cur0[e.x], 1); inc[s0] = i;
    int s1 = atomicAdd(&cur1[e.y], 1); inc[s1] = i;
}

__global__ void sort_k(int* __restrict__ inc, const int* __restrict__ segoff,
                       const int* __restrict__ split, int nv) {
    int v = blockIdx.x * blockDim.x + threadIdx.x;
    if (v >= nv) return;
    int lo = segoff[v], mid = split[v], hi = segoff[v + 1];
    for (int a = lo + 1; a < mid; ++a) {
        int key = inc[a]; int b = a - 1;
        while (b >= lo && inc[b] > key) { inc[b + 1] = inc[b]; --b; }
        inc[b + 1] = key;
    }
    for (int a = mid + 1; a < hi; ++a) {
        int key = inc[a]; int b = a - 1;
        while (b >= mid && inc[b] > key) { inc[b + 1] = inc[b]; --b; }
        inc[b + 1] = key;
    }
}

// ---- CG kernels ----
__global__ void init_k(const float* __restrict__ rhs, float* __restrict__ x,
                       float* __restrict__ r, float* __restrict__ p,
                       float* __restrict__ prod, int n) {
    int j = blockIdx.x * blockDim.x + threadIdx.x;
    if (j >= n) return;
    float b = rhs[j];
    x[j] = 0.0f; r[j] = b; p[j] = b;
    prod[j] = fmul32(b, b);
}

// matvec per vertex (np.add.at order) + prod = p*Ap (for pAp chain)
__global__ void mv_k(const int2* __restrict__ ed, const float* __restrict__ pos,
                     const float* __restrict__ rl, const float* __restrict__ p,
                     const float* __restrict__ mass, const int* __restrict__ inc,
                     const int* __restrict__ segoff, const int* __restrict__ split,
                     float* __restrict__ Ap, float* __restrict__ prod, int nv) {
    int v = blockIdx.x * blockDim.x + threadIdx.x;
    if (v >= nv) return;
    int lo = segoff[v], mid = split[v], hi = segoff[v + 1];
    float a0 = 0.0f, a1 = 0.0f, a2 = 0.0f;
    for (int k = lo; k < mid; ++k) {
        int e = inc[k]; float f[3];
        edge_force(ed[e], e, pos, rl, p, f);
        a0 = fadd32(a0, f[0]); a1 = fadd32(a1, f[1]); a2 = fadd32(a2, f[2]);
    }
    for (int k = mid; k < hi; ++k) {
        int e = inc[k]; float f[3];
        edge_force(ed[e], e, pos, rl, p, f);
        a0 = fadd32(a0, -f[0]); a1 = fadd32(a1, -f[1]); a2 = fadd32(a2, -f[2]);
    }
    const float h2 = (float)(0.01 * 0.01);   // f32(H*H): f64 product, one cast
    int j = 3 * v; float m = mass[v];
    float p0 = p[j], p1 = p[j + 1], p2 = p[j + 2];
    float A0 = fsub32(fmul32(m, p0), fmul32(h2, a0));
    float A1 = fsub32(fmul32(m, p1), fmul32(h2, a1));
    float A2 = fsub32(fmul32(m, p2), fmul32(h2, a2));
    Ap[j + 0] = A0; Ap[j + 1] = A1; Ap[j + 2] = A2;
    prod[j + 0] = fmul32(p0, A0);
    prod[j + 1] = fmul32(p1, A1);
    prod[j + 2] = fmul32(p2, A2);
}

#define SCHED_FENCE() __builtin_amdgcn_sched_barrier(0)
#define ACC4(v) { s = fadd32(s, (v).x); s = fadd32(s, (v).y); \
                  s = fadd32(s, (v).z); s = fadd32(s, (v).w); }
#define G8_DECL(P) float4 P##0, P##1, P##2, P##3, P##4, P##5, P##6, P##7;
#define G8_LOAD(P, b4, base) { P##0=(b4)[(base)+0]; P##1=(b4)[(base)+1]; \
    P##2=(b4)[(base)+2]; P##3=(b4)[(base)+3]; P##4=(b4)[(base)+4]; \
    P##5=(b4)[(base)+5]; P##6=(b4)[(base)+6]; P##7=(b4)[(base)+7]; }
#define G8_ACC(P) { ACC4(P##0) ACC4(P##1) ACC4(P##2) ACC4(P##3) \
                    ACC4(P##4) ACC4(P##5) ACC4(P##6) ACC4(P##7) }

// Serial sequential-f32 add chain (numpy no-CBLAS FLOAT_dot order).
// Producers stage tile t+1 HBM->LDS while thread 0 chains tile t.
// Thread 0: distance-2 register prefetch, 3-way rotation (A,B,C), with
// __builtin_amdgcn_sched_barrier(0) pinning source order — R14's version
// let the scheduler sink the prefetch back to its use (VGPR stayed 88).
// With order pinned, ACC(A) waits only lgkmcnt(16) (B,C outstanding) and
// A's loads have had ~2 group-times (~300 cyc) to complete.
// Values and order bit-identical to numpy: float sum=0; for i: sum+=prod[i].
__global__ void __launch_bounds__(CHAIN_TB, 1)
chain_k(const float* __restrict__ prod, float* __restrict__ out, int n) {
    __shared__ float buf[2][TILE];
    int tid = threadIdx.x;
    int ntiles = (n + TILE - 1) / TILE;
    {
        int lim = (TILE < n) ? TILE : n;
        for (int i = tid; i < lim; i += CHAIN_TB) buf[0][i] = prod[i];
    }
    __syncthreads();
    float s = 0.0f;
    for (int t = 0; t < ntiles; ++t) {
        if (t + 1 < ntiles) {                 // stage next tile while chaining
            int base = (t + 1) * TILE;
            int lim = n - base; if (lim > TILE) lim = TILE;
            float* dst = buf[(t + 1) & 1];
            for (int i = tid; i < lim; i += CHAIN_TB) dst[i] = prod[base + i];
        }
        if (tid == 0) {
            const float* b = buf[t & 1];
            int cnt = n - t * TILE; if (cnt > TILE) cnt = TILE;
            const float4* b4 = (const float4*)b;
            int c4 = cnt >> 2;      // float4 count
            int ng = c4 >> 3;       // groups of 8 float4 (32 floats)
            int g = 0;
            if (ng >= 5) {
                G8_DECL(A) G8_DECL(B) G8_DECL(C)
                G8_LOAD(A, b4, 0)
                SCHED_FENCE();
                G8_LOAD(B, b4, 8)
                SCHED_FENCE();
                for (; g + 5 <= ng; g += 3) {   // all prefetch bases <= ng-1
                    G8_LOAD(C, b4, (g + 2) << 3)  SCHED_FENCE();
                    G8_ACC(A)                     SCHED_FENCE();
                    G8_LOAD(A, b4, (g + 3) << 3)  SCHED_FENCE();
                    G8_ACC(B)                     SCHED_FENCE();
                    G8_LOAD(B, b4, (g + 4) << 3)  SCHED_FENCE();
                    G8_ACC(C)                     SCHED_FENCE();
                }
                G8_ACC(A)   // group g
                G8_ACC(B)   // group g+1   (rem groups = 2..4, A/B valid)
                g += 2;
            }
            for (; g < ng; ++g) {   // <=2 exposed groups per tile
                G8_DECL(D)
                G8_LOAD(D, b4, g << 3)
                G8_ACC(D)
            }
            for (int i = ng << 3; i < c4; ++i) { float4 v = b4[i]; ACC4(v) }
            for (int k = c4 << 2; k < cnt; ++k) s = fadd32(s, b[k]);
        }
        __syncthreads();   // tile t+1 staged AND thread0 done with buf[t&1]
    }
    if (tid == 0) out[0] = s;
}

// x += alpha p ; r -= alpha Ap ; prod = r_new*r_new (for rs chain)
// numpy 1.x scalar-scalar promotion: alpha = f32( (f64)rs / ((f64)pAp + 1e-8) )
__global__ void xr_k(float* __restrict__ x, float* __restrict__ r,
                     const float* __restrict__ p, const float* __restrict__ Ap,
                     float* __restrict__ prod, const float* __restrict__ scal,
                     int it, int n) {
    int j = blockIdx.x * blockDim.x + threadIdx.x;
    if (j >= n) return;
    float alpha = (float)((double)scal[it] / ((double)scal[PAP_OFF + it] + 1e-8));
    x[j] = fadd32(x[j], fmul32(alpha, p[j]));
    float rn = fsub32(r[j], fmul32(alpha, Ap[j]));
    r[j] = rn;
    prod[j] = fmul32(rn, rn);
}

__global__ void p_k(const float* __restrict__ r, float* __restrict__ p,
                    const float* __restrict__ scal, int it, int n) {
    int j = blockIdx.x * blockDim.x + threadIdx.x;
    if (j >= n) return;
    float beta = (float)((double)scal[it + 1] / ((double)scal[it] + 1e-8));
    p[j] = fadd32(r[j], fmul32(beta, p[j]));
}

extern "C" void kernel_launch(void* const* d_in, const int* in_sizes, int n_in,
                              void* d_out, int out_size, void* d_ws, size_t ws_size,
                              hipStream_t stream) {
    const float* rhs  = (const float*)d_in[0];
    const float* pos  = (const float*)d_in[1];
    const float* mass = (const float*)d_in[2];
    const float* rl   = (const float*)d_in[3];
    const int2*  ed   = (const int2*)d_in[4];
    float* x = (float*)d_out;

    int NV = in_sizes[0] / 3;
    int NE = in_sizes[3];
    int n3 = NV * 3;

    char* w = (char*)d_ws;
    float* r    = (float*)w;  w += (size_t)n3 * sizeof(float);
    float* p    = (float*)w;  w += (size_t)n3 * sizeof(float);
    float* Ap   = (float*)w;  w += (size_t)n3 * sizeof(float);
    float* prod = (float*)w;  w += (size_t)n3 * sizeof(float);
    int*   inc  = (int*)w;    w += (size_t)2 * NE * sizeof(int);
    int*   cnt0 = (int*)w;    w += (size_t)NV * sizeof(int);
    int*   cnt1 = (int*)w;    w += (size_t)NV * sizeof(int);
    int*   segoff = (int*)w;  w += (size_t)(NV + 1) * sizeof(int);
    int*   split  = (int*)w;  w += (size_t)NV * sizeof(int);
    int*   cur0   = (int*)w;  w += (size_t)NV * sizeof(int);
    int*   cur1   = (int*)w;  w += (size_t)NV * sizeof(int);
    float* scal   = (float*)w;

    hipMemsetAsync(cnt0, 0, (size_t)2 * NV * sizeof(int), stream);  // cnt0+cnt1 adjacent

    const int tb = 256;
    int gE = (NE + tb - 1) / tb;
    int gV = (NV + tb - 1) / tb;
    int g3 = (n3 + tb - 1) / tb;

    count_k<<<gE, tb, 0, stream>>>(ed, cnt0, cnt1, NE);
    scan_k<<<1, 1024, 0, stream>>>(cnt0, cnt1, segoff, split, cur0, cur1, NV);
    fill_k<<<gE, tb, 0, stream>>>(ed, cur0, cur1, inc, NE);
    sort_k<<<gV, tb, 0, stream>>>(inc, segoff, split, NV);

    init_k<<<g3, tb, 0, stream>>>(rhs, x, r, p, prod, n3);
    chain_k<<<1, CHAIN_TB, 0, stream>>>(prod, &scal[0], n3);   // rs0 = vdot(b,b)

    for (int it = 0; it < CG_ITERS; ++it) {
        mv_k<<<gV, tb, 0, stream>>>(ed, pos, rl, p, mass, inc, segoff, split, Ap, prod, NV);
        chain_k<<<1, CHAIN_TB, 0, stream>>>(prod, &scal[PAP_OFF + it], n3);
        xr_k<<<g3, tb, 0, stream>>>(x, r, p, Ap, prod, scal, it, n3);
        if (it + 1 < CG_ITERS) {   // scal[30] and final p never affect x
            chain_k<<<1, CHAIN_TB, 0, stream>>>(prod, &scal[it + 1], n3);
            p_k<<<g3, tb, 0, stream>>>(r, p, scal, it, n3);
        }
    }
}